// Round 1
// baseline (251.716 us; speedup 1.0000x reference)
//
#include <hip/hip_runtime.h>
#include <hip/hip_bf16.h>

// Problem constants
#define BB 4
#define SS 1024
#define DD 1024
#define HH 16
#define HDIM 64
#define MM (BB*SS)   // 4096

typedef __attribute__((ext_vector_type(8))) short  bf16x8;
typedef __attribute__((ext_vector_type(4))) float  f32x4v;

static __device__ __forceinline__ unsigned short f2bf(float f) {
    union { float f; unsigned u; } v; v.f = f;
    unsigned r = v.u + 0x7fff + ((v.u >> 16) & 1);   // round-to-nearest-even
    return (unsigned short)(r >> 16);
}

// ---------------------------------------------------------------------------
// Kernel 1: QKV projection.  C[m,n] = sum_k x[m,k] * W[n,k]  (torch Linear x@W.T)
// Output written as bf16 in [b, h, s, hd] layout.
// Tile 128x128, BK=32, 256 threads (4 waves, 2x2), each wave 64x64 (4x4 frags).
// ---------------------------------------------------------------------------
__global__ __launch_bounds__(256) void qkv_gemm(
    const float* __restrict__ x,
    const float* __restrict__ Wq, const float* __restrict__ Wk, const float* __restrict__ Wv,
    unsigned short* __restrict__ q_ws, unsigned short* __restrict__ k_ws,
    unsigned short* __restrict__ v_ws)
{
    const int bn = blockIdx.x;          // 0..7   (N tiles)
    const int bm = blockIdx.y;          // 0..31  (M tiles)
    const int bz = blockIdx.z;          // 0..2   (which projection)
    const float* W;
    unsigned short* outp;
    if (bz == 0)      { W = Wq; outp = q_ws; }
    else if (bz == 1) { W = Wk; outp = k_ws; }
    else              { W = Wv; outp = v_ws; }

    const int tid = threadIdx.x;
    const int wid = tid >> 6, lane = tid & 63;
    const int wr = wid >> 1, wc = wid & 1;
    const int lhi = lane >> 4, llo = lane & 15;

    __shared__ unsigned short As[128 * 40];
    __shared__ unsigned short Bs[128 * 40];

    f32x4v acc[4][4] = {};
    const int m0 = bm * 128, n0 = bn * 128;

    for (int kt = 0; kt < DD / 32; ++kt) {
        __syncthreads();
        // stage A (x tile) and B (W tile): 128x32 f32 -> bf16
        #pragma unroll
        for (int i = 0; i < 4; ++i) {
            int idx = tid + i * 256;
            int row = idx >> 3, c4 = (idx & 7) * 4;
            f32x4v xv = *(const f32x4v*)(x + (size_t)(m0 + row) * DD + kt * 32 + c4);
            unsigned p0 = (unsigned)f2bf(xv[0]) | ((unsigned)f2bf(xv[1]) << 16);
            unsigned p1 = (unsigned)f2bf(xv[2]) | ((unsigned)f2bf(xv[3]) << 16);
            uint2 pk; pk.x = p0; pk.y = p1;
            *(uint2*)(As + row * 40 + c4) = pk;

            f32x4v wv = *(const f32x4v*)(W + (size_t)(n0 + row) * DD + kt * 32 + c4);
            unsigned q0 = (unsigned)f2bf(wv[0]) | ((unsigned)f2bf(wv[1]) << 16);
            unsigned q1 = (unsigned)f2bf(wv[2]) | ((unsigned)f2bf(wv[3]) << 16);
            uint2 qk; qk.x = q0; qk.y = q1;
            *(uint2*)(Bs + row * 40 + c4) = qk;
        }
        __syncthreads();

        bf16x8 af[4], bfr[4];
        #pragma unroll
        for (int i = 0; i < 4; ++i)
            af[i] = *(const bf16x8*)(As + (wr * 64 + i * 16 + llo) * 40 + lhi * 8);
        #pragma unroll
        for (int i = 0; i < 4; ++i)
            bfr[i] = *(const bf16x8*)(Bs + (wc * 64 + i * 16 + llo) * 40 + lhi * 8);

        #pragma unroll
        for (int i = 0; i < 4; ++i)
            #pragma unroll
            for (int j = 0; j < 4; ++j)
                acc[i][j] = __builtin_amdgcn_mfma_f32_16x16x32_bf16(af[i], bfr[j], acc[i][j], 0, 0, 0);
    }

    // epilogue: write bf16 in [b, h, s, hd] layout
    #pragma unroll
    for (int i = 0; i < 4; ++i) {
        #pragma unroll
        for (int j = 0; j < 4; ++j) {
            #pragma unroll
            for (int r = 0; r < 4; ++r) {
                int mrow = m0 + wr * 64 + i * 16 + lhi * 4 + r;
                int ncol = n0 + wc * 64 + j * 16 + llo;
                float val = acc[i][j][r];
                size_t idx = ((size_t)((mrow >> 10) * HH + (ncol >> 6)) * SS + (mrow & 1023)) * HDIM + (ncol & 63);
                outp[idx] = f2bf(val);
            }
        }
    }
}

// ---------------------------------------------------------------------------
// Kernel 2: flash-style attention per (q-tile, b*h).
// Block = 256 threads (4 waves), QBLK=64 (16 rows/wave), KVBLK=64.
// ---------------------------------------------------------------------------
__global__ __launch_bounds__(256) void attn_kernel(
    const unsigned short* __restrict__ q_ws,
    const unsigned short* __restrict__ k_ws,
    const unsigned short* __restrict__ v_ws,
    unsigned short* __restrict__ ctx)
{
    const int qt = blockIdx.x;   // 0..15
    const int bh = blockIdx.y;   // 0..63
    const int tid = threadIdx.x, wid = tid >> 6, lane = tid & 63;
    const int lhi = lane >> 4, llo = lane & 15;

    __shared__ unsigned short Ks[64 * 72];
    __shared__ unsigned short VT[64 * 72];     // V transposed: [hd][kv]
    __shared__ unsigned short Ps[4][16 * 72];  // per-wave P tile

    const size_t basekv = (size_t)bh * SS * HDIM;
    const int qrow0 = qt * 64 + wid * 16;

    // Q fragments in registers (2 k-steps over hd=64)
    bf16x8 aq[2];
    #pragma unroll
    for (int ks = 0; ks < 2; ++ks)
        aq[ks] = *(const bf16x8*)(q_ws + basekv + (size_t)(qrow0 + llo) * HDIM + ks * 32 + lhi * 8);

    f32x4v o[4] = {};
    float m_run[4], l_run[4];
    #pragma unroll
    for (int j = 0; j < 4; ++j) { m_run[j] = -1e30f; l_run[j] = 0.f; }

    for (int kvt = 0; kvt < 16; ++kvt) {
        __syncthreads();
        // stage K rows [64][64] bf16
        #pragma unroll
        for (int i = 0; i < 2; ++i) {
            int idx = tid + i * 256;
            int row = idx >> 3, c8 = (idx & 7) * 8;
            *(bf16x8*)(Ks + row * 72 + c8) =
                *(const bf16x8*)(k_ws + basekv + (size_t)(kvt * 64 + row) * HDIM + c8);
        }
        // stage V transposed
        #pragma unroll
        for (int i = 0; i < 16; ++i) {
            int idx = tid + i * 256;
            int kv = idx >> 6, hd = idx & 63;
            VT[hd * 72 + kv] = v_ws[basekv + (size_t)(kvt * 64 + kv) * HDIM + hd];
        }
        __syncthreads();

        // S = Q K^T
        f32x4v s[4] = {};
        #pragma unroll
        for (int ni = 0; ni < 4; ++ni) {
            #pragma unroll
            for (int ks = 0; ks < 2; ++ks) {
                bf16x8 bk = *(const bf16x8*)(Ks + (ni * 16 + llo) * 72 + ks * 32 + lhi * 8);
                s[ni] = __builtin_amdgcn_mfma_f32_16x16x32_bf16(aq[ks], bk, s[ni], 0, 0, 0);
            }
        }
        #pragma unroll
        for (int ni = 0; ni < 4; ++ni) s[ni] = s[ni] * 0.125f;   // 1/sqrt(64)

        // online softmax per row (rows j=0..3 per lane, cols across 16-lane group x 4 blocks)
        #pragma unroll
        for (int j = 0; j < 4; ++j) {
            float tmax = fmaxf(fmaxf(s[0][j], s[1][j]), fmaxf(s[2][j], s[3][j]));
            #pragma unroll
            for (int off = 1; off < 16; off <<= 1)
                tmax = fmaxf(tmax, __shfl_xor(tmax, off, 64));
            float mn = fmaxf(m_run[j], tmax);
            float alpha = __expf(m_run[j] - mn);
            float rs = 0.f;
            #pragma unroll
            for (int ni = 0; ni < 4; ++ni) {
                float p = __expf(s[ni][j] - mn);
                s[ni][j] = p;
                rs += p;
            }
            #pragma unroll
            for (int off = 1; off < 16; off <<= 1)
                rs += __shfl_xor(rs, off, 64);
            l_run[j] = l_run[j] * alpha + rs;
            m_run[j] = mn;
            #pragma unroll
            for (int ni = 0; ni < 4; ++ni) o[ni][j] *= alpha;
        }

        // P -> LDS (per-wave region), then read back in A-fragment layout
        unsigned short* pw = Ps[wid];
        #pragma unroll
        for (int ni = 0; ni < 4; ++ni)
            #pragma unroll
            for (int j = 0; j < 4; ++j)
                pw[(lhi * 4 + j) * 72 + ni * 16 + llo] = f2bf(s[ni][j]);
        asm volatile("s_waitcnt lgkmcnt(0)" ::: "memory");

        // O += P V
        #pragma unroll
        for (int ks = 0; ks < 2; ++ks) {
            bf16x8 pa = *(const bf16x8*)(pw + llo * 72 + ks * 32 + lhi * 8);
            #pragma unroll
            for (int ni = 0; ni < 4; ++ni) {
                bf16x8 bv = *(const bf16x8*)(VT + (ni * 16 + llo) * 72 + ks * 32 + lhi * 8);
                o[ni] = __builtin_amdgcn_mfma_f32_16x16x32_bf16(pa, bv, o[ni], 0, 0, 0);
            }
        }
    }

    // epilogue: ctx[b, s, h*hd] bf16
    const int b = bh >> 4, h = bh & 15;
    #pragma unroll
    for (int ni = 0; ni < 4; ++ni) {
        #pragma unroll
        for (int j = 0; j < 4; ++j) {
            int srow = qrow0 + lhi * 4 + j;
            int hd = ni * 16 + llo;
            float val = o[ni][j] / l_run[j];
            ctx[(size_t)(b * SS + srow) * DD + h * HDIM + hd] = f2bf(val);
        }
    }
}

// ---------------------------------------------------------------------------
// Kernel 3: output projection.  out[m,n] = sum_k ctx[m,k] * Wo[n,k] + bo[n]
// ---------------------------------------------------------------------------
__global__ __launch_bounds__(256) void out_gemm(
    const unsigned short* __restrict__ ctx,
    const float* __restrict__ Wo,
    const float* __restrict__ bo,
    float* __restrict__ out)
{
    const int bn = blockIdx.x;          // 0..7
    const int bm = blockIdx.y;          // 0..31
    const int tid = threadIdx.x;
    const int wid = tid >> 6, lane = tid & 63;
    const int wr = wid >> 1, wc = wid & 1;
    const int lhi = lane >> 4, llo = lane & 15;

    __shared__ unsigned short As[128 * 40];
    __shared__ unsigned short Bs[128 * 40];

    f32x4v acc[4][4] = {};
    const int m0 = bm * 128, n0 = bn * 128;

    for (int kt = 0; kt < DD / 32; ++kt) {
        __syncthreads();
        // stage A (ctx, already bf16): 128x32
        #pragma unroll
        for (int i = 0; i < 2; ++i) {
            int idx = tid + i * 256;
            int row = idx >> 2, c8 = (idx & 3) * 8;
            *(bf16x8*)(As + row * 40 + c8) =
                *(const bf16x8*)(ctx + (size_t)(m0 + row) * DD + kt * 32 + c8);
        }
        // stage B (Wo f32 -> bf16)
        #pragma unroll
        for (int i = 0; i < 4; ++i) {
            int idx = tid + i * 256;
            int row = idx >> 3, c4 = (idx & 7) * 4;
            f32x4v wv = *(const f32x4v*)(Wo + (size_t)(n0 + row) * DD + kt * 32 + c4);
            unsigned q0 = (unsigned)f2bf(wv[0]) | ((unsigned)f2bf(wv[1]) << 16);
            unsigned q1 = (unsigned)f2bf(wv[2]) | ((unsigned)f2bf(wv[3]) << 16);
            uint2 qk; qk.x = q0; qk.y = q1;
            *(uint2*)(Bs + row * 40 + c4) = qk;
        }
        __syncthreads();

        bf16x8 af[4], bfr[4];
        #pragma unroll
        for (int i = 0; i < 4; ++i)
            af[i] = *(const bf16x8*)(As + (wr * 64 + i * 16 + llo) * 40 + lhi * 8);
        #pragma unroll
        for (int i = 0; i < 4; ++i)
            bfr[i] = *(const bf16x8*)(Bs + (wc * 64 + i * 16 + llo) * 40 + lhi * 8);

        #pragma unroll
        for (int i = 0; i < 4; ++i)
            #pragma unroll
            for (int j = 0; j < 4; ++j)
                acc[i][j] = __builtin_amdgcn_mfma_f32_16x16x32_bf16(af[i], bfr[j], acc[i][j], 0, 0, 0);
    }

    // epilogue with bias, f32 out
    #pragma unroll
    for (int j = 0; j < 4; ++j) {
        int ncol = n0 + wc * 64 + j * 16 + llo;
        float bias = bo[ncol];
        #pragma unroll
        for (int i = 0; i < 4; ++i) {
            #pragma unroll
            for (int r = 0; r < 4; ++r) {
                int mrow = m0 + wr * 64 + i * 16 + lhi * 4 + r;
                out[(size_t)mrow * DD + ncol] = acc[i][j][r] + bias;
            }
        }
    }
}

extern "C" void kernel_launch(void* const* d_in, const int* in_sizes, int n_in,
                              void* d_out, int out_size, void* d_ws, size_t ws_size,
                              hipStream_t stream) {
    const float* x  = (const float*)d_in[0];
    const float* Wq = (const float*)d_in[1];
    const float* Wk = (const float*)d_in[2];
    const float* Wv = (const float*)d_in[3];
    const float* Wo = (const float*)d_in[4];
    const float* bo = (const float*)d_in[5];
    float* out = (float*)d_out;

    // workspace layout (bf16): Q, K, V in [b,h,s,hd]; ctx in [b,s,d]
    unsigned short* q_ws = (unsigned short*)d_ws;
    unsigned short* k_ws = q_ws + (size_t)MM * DD;
    unsigned short* v_ws = k_ws + (size_t)MM * DD;
    unsigned short* ctx  = v_ws + (size_t)MM * DD;

    qkv_gemm<<<dim3(8, 32, 3), 256, 0, stream>>>(x, Wq, Wk, Wv, q_ws, k_ws, v_ws);
    attn_kernel<<<dim3(16, 64), 256, 0, stream>>>(q_ws, k_ws, v_ws, ctx);
    out_gemm<<<dim3(8, 32), 256, 0, stream>>>(ctx, Wo, bo, out);
}

// Round 11
// 240.653 us; speedup vs baseline: 1.0460x; 1.0460x over previous
//
#include <hip/hip_runtime.h>
#include <hip/hip_bf16.h>

// Problem constants
#define BB 4
#define SS 1024
#define DD 1024
#define HH 16
#define HDIM 64
#define MM (BB*SS)   // 4096

typedef __attribute__((ext_vector_type(8))) short  bf16x8;
typedef __attribute__((ext_vector_type(4))) float  f32x4v;
typedef __attribute__((ext_vector_type(4))) unsigned short u16x4;

static __device__ __forceinline__ unsigned short f2bf(float f) {
    union { float f; unsigned u; } v; v.f = f;
    unsigned r = v.u + 0x7fff + ((v.u >> 16) & 1);   // round-to-nearest-even
    return (unsigned short)(r >> 16);
}

// async global->LDS, 16B per lane. LDS dest must be wave-uniform base (HW adds lane*16).
static __device__ __forceinline__ void gload16(const void* g, const void* lds_uniform_base) {
    __builtin_amdgcn_global_load_lds(
        (const __attribute__((address_space(1))) unsigned int*)(uintptr_t)g,
        (__attribute__((address_space(3))) unsigned int*)(uintptr_t)lds_uniform_base,
        16, 0, 0);
}

// ---------------------------------------------------------------------------
// Kernel 0: f32 -> bf16 conversion of x only (8 MB out).  4096 blocks x 256.
// ---------------------------------------------------------------------------
__global__ __launch_bounds__(256) void convert_x(
    const float* __restrict__ x, unsigned short* __restrict__ xb)
{
    size_t i = ((size_t)blockIdx.x * 256 + threadIdx.x) * 4;
    f32x4v v = *(const f32x4v*)(x + i);
    u16x4 o;
    o[0] = f2bf(v[0]); o[1] = f2bf(v[1]); o[2] = f2bf(v[2]); o[3] = f2bf(v[3]);
    *(u16x4*)(xb + i) = o;
}

// ---------------------------------------------------------------------------
// Kernel 1: QKV projection.  A (x, bf16) via global_load_lds; B (W, f32) via
// reg-stage + convert + ds_write.  C[m,n] = sum_k x[m,k]*W[n,k];
// out bf16 [b,h,s,hd]; Q pre-scaled by 1/8.
// ---------------------------------------------------------------------------
__global__ __launch_bounds__(256) void qkv_gemm(
    const unsigned short* __restrict__ xb,
    const float* __restrict__ Wq, const float* __restrict__ Wk,
    const float* __restrict__ Wv,
    unsigned short* __restrict__ q_ws, unsigned short* __restrict__ k_ws,
    unsigned short* __restrict__ v_ws)
{
    const int bn = blockIdx.x, bm = blockIdx.y, bz = blockIdx.z;
    const float* W = (bz == 0) ? Wq : (bz == 1) ? Wk : Wv;
    unsigned short* outp = (bz == 0) ? q_ws : (bz == 1) ? k_ws : v_ws;

    const int tid = threadIdx.x;
    const int wid = tid >> 6, lane = tid & 63;
    const int wr = wid >> 1, wc = wid & 1;
    const int lhi = lane >> 4, llo = lane & 15;

    __shared__ unsigned short As[2][128 * 32];
    __shared__ unsigned short Bs[2][128 * 32];

    const int m0 = bm * 128, n0 = bn * 128;
    const int brow = tid >> 1, bhalf = tid & 1;   // B staging: 16 f32 per thread

    auto stageA = [&](int buf, int kt) {
        #pragma unroll
        for (int j = 0; j < 2; ++j) {
            int chunk = j * 256 + wid * 64 + lane;
            int row = chunk >> 2, sub = chunk & 3;
            gload16(xb + (size_t)(m0 + row) * DD + kt * 32 + sub * 8,
                    &As[buf][(j * 256 + wid * 64) * 8]);
        }
    };
    auto loadB = [&](int kt, f32x4v* r) {
        const float* p = W + (size_t)(n0 + brow) * DD + kt * 32 + bhalf * 16;
        r[0] = *(const f32x4v*)(p);
        r[1] = *(const f32x4v*)(p + 4);
        r[2] = *(const f32x4v*)(p + 8);
        r[3] = *(const f32x4v*)(p + 12);
    };
    auto writeB = [&](int buf, const f32x4v* r) {
        bf16x8 p0, p1;
        #pragma unroll
        for (int e = 0; e < 4; ++e) {
            p0[e]     = (short)f2bf(r[0][e]);
            p0[e + 4] = (short)f2bf(r[1][e]);
            p1[e]     = (short)f2bf(r[2][e]);
            p1[e + 4] = (short)f2bf(r[3][e]);
        }
        *(bf16x8*)&Bs[buf][brow * 32 + bhalf * 16]     = p0;
        *(bf16x8*)&Bs[buf][brow * 32 + bhalf * 16 + 8] = p1;
    };

    f32x4v acc[4][4] = {};
    f32x4v br[4];

    stageA(0, 0);
    loadB(0, br);
    writeB(0, br);
    __syncthreads();

    for (int kt = 0; kt < 32; ++kt) {
        int cur = kt & 1;
        if (kt < 31) { loadB(kt + 1, br); stageA(cur ^ 1, kt + 1); }

        bf16x8 af[4], bfr[4];
        #pragma unroll
        for (int i = 0; i < 4; ++i)
            af[i] = *(const bf16x8*)&As[cur][(wr * 64 + i * 16 + llo) * 32 + lhi * 8];
        #pragma unroll
        for (int i = 0; i < 4; ++i)
            bfr[i] = *(const bf16x8*)&Bs[cur][(wc * 64 + i * 16 + llo) * 32 + lhi * 8];

        #pragma unroll
        for (int i = 0; i < 4; ++i)
            #pragma unroll
            for (int j = 0; j < 4; ++j)
                acc[i][j] = __builtin_amdgcn_mfma_f32_16x16x32_bf16(af[i], bfr[j], acc[i][j], 0, 0, 0);

        if (kt < 31) writeB(cur ^ 1, br);
        __syncthreads();
    }

    // epilogue: write bf16 in [b, h, s, hd] layout; scale Q by 1/sqrt(hd)=0.125
    const float sc = (bz == 0) ? 0.125f : 1.0f;
    #pragma unroll
    for (int i = 0; i < 4; ++i) {
        #pragma unroll
        for (int j = 0; j < 4; ++j) {
            #pragma unroll
            for (int r = 0; r < 4; ++r) {
                int mrow = m0 + wr * 64 + i * 16 + lhi * 4 + r;
                int ncol = n0 + wc * 64 + j * 16 + llo;
                float val = acc[i][j][r] * sc;
                size_t idx = ((size_t)((mrow >> 10) * HH + (ncol >> 6)) * SS + (mrow & 1023)) * HDIM + (ncol & 63);
                outp[idx] = f2bf(val);
            }
        }
    }
}

// ---------------------------------------------------------------------------
// Kernel 2: flash attention.  QBLK=64 (16 rows/wave), KVBLK=64, dbuf staging.
// K in LDS: linear dest, XOR-swizzled global source (rule 21), swizzled read.
// V in LDS: linear row-major [64][64]; PV B-fragment via 8x ds_read_u16
// column reads (adjacent 2B cols within 16-lane group -> conflict-light).
// (tr_b16 inline asm removed for crash bisect.)
// ---------------------------------------------------------------------------
__global__ __launch_bounds__(256) void attn_kernel(
    const unsigned short* __restrict__ q_ws,
    const unsigned short* __restrict__ k_ws,
    const unsigned short* __restrict__ v_ws,
    unsigned short* __restrict__ ctx)
{
    const int qt = blockIdx.x;   // 0..15
    const int bh = blockIdx.y;   // 0..63
    const int tid = threadIdx.x, wid = tid >> 6, lane = tid & 63;
    const int lhi = lane >> 4, llo = lane & 15;

    __shared__ unsigned short Ks[2][64 * 64];   // swizzled row-major [64][64]
    __shared__ unsigned short Vs[2][64 * 64];   // linear row-major [64][64]
    __shared__ unsigned short Ps[4][16 * 72];   // per-wave P tile

    const size_t basekv = (size_t)bh * SS * HDIM;
    const int qrow0 = qt * 64 + wid * 16;

    // Q fragments in registers (already pre-scaled by 1/8 in qkv epilogue)
    bf16x8 aq[2];
    #pragma unroll
    for (int ks = 0; ks < 2; ++ks)
        aq[ks] = *(const bf16x8*)(q_ws + basekv + (size_t)(qrow0 + llo) * HDIM + ks * 32 + lhi * 8);

    auto stage = [&](int buf, int kvt) {
        #pragma unroll
        for (int j = 0; j < 2; ++j) {
            int chunk = j * 256 + wid * 64 + lane;
            int krow = chunk >> 3, ksub = chunk & 7;
            // K: linear dest, inverse-swizzled source
            gload16(k_ws + basekv + (size_t)(kvt * 64 + krow) * HDIM + ((ksub ^ (krow & 7)) * 8),
                    &Ks[buf][(j * 256 + wid * 64) * 8]);
            // V: linear dest, linear source
            gload16(v_ws + basekv + (size_t)(kvt * 64 + krow) * HDIM + ksub * 8,
                    &Vs[buf][(j * 256 + wid * 64) * 8]);
        }
    };

    f32x4v o[4] = {};
    float m_run[4], l_run[4];
    #pragma unroll
    for (int j = 0; j < 4; ++j) { m_run[j] = -1e30f; l_run[j] = 0.f; }

    stage(0, 0);
    __syncthreads();

    for (int kvt = 0; kvt < 16; ++kvt) {
        const int cur = kvt & 1;
        if (kvt < 15) stage(cur ^ 1, kvt + 1);

        // ---- S = Q K^T (swizzled read of K) ----
        const char* kbuf = (const char*)&Ks[cur][0];
        f32x4v s[4] = {};
        #pragma unroll
        for (int ni = 0; ni < 4; ++ni) {
            int row = ni * 16 + llo;
            #pragma unroll
            for (int ks = 0; ks < 2; ++ks) {
                int colb = (ks * 64 + lhi * 16) ^ ((llo & 7) << 4);
                bf16x8 bk = *(const bf16x8*)(kbuf + row * 128 + colb);
                s[ni] = __builtin_amdgcn_mfma_f32_16x16x32_bf16(aq[ks], bk, s[ni], 0, 0, 0);
            }
        }

        // ---- online softmax (rows j per lane, cols across 16-lane groups x 4 blocks) ----
        #pragma unroll
        for (int j = 0; j < 4; ++j) {
            float tmax = fmaxf(fmaxf(s[0][j], s[1][j]), fmaxf(s[2][j], s[3][j]));
            #pragma unroll
            for (int off = 1; off < 16; off <<= 1)
                tmax = fmaxf(tmax, __shfl_xor(tmax, off, 64));
            float mn = fmaxf(m_run[j], tmax);
            float alpha = __expf(m_run[j] - mn);
            float rs = 0.f;
            #pragma unroll
            for (int ni = 0; ni < 4; ++ni) {
                float p = __expf(s[ni][j] - mn);
                s[ni][j] = p;
                rs += p;
            }
            #pragma unroll
            for (int off = 1; off < 16; off <<= 1)
                rs += __shfl_xor(rs, off, 64);
            l_run[j] = l_run[j] * alpha + rs;
            m_run[j] = mn;
            #pragma unroll
            for (int ni = 0; ni < 4; ++ni) o[ni][j] *= alpha;
        }

        // ---- P -> per-wave LDS, read back as A-fragments ----
        unsigned short* pw = Ps[wid];
        #pragma unroll
        for (int ni = 0; ni < 4; ++ni)
            #pragma unroll
            for (int j = 0; j < 4; ++j)
                pw[(lhi * 4 + j) * 72 + ni * 16 + llo] = f2bf(s[ni][j]);

        asm volatile("s_waitcnt lgkmcnt(0)" ::: "memory");
        __builtin_amdgcn_sched_barrier(0);

        bf16x8 pa[2];
        #pragma unroll
        for (int ks = 0; ks < 2; ++ks)
            pa[ks] = *(const bf16x8*)(pw + llo * 72 + ks * 32 + lhi * 8);

        // ---- O += P V  (V column reads: 8x ds_read_u16 per fragment) ----
        const unsigned short* vbuf = &Vs[cur][0];
        #pragma unroll
        for (int ks = 0; ks < 2; ++ks) {
            #pragma unroll
            for (int ni = 0; ni < 4; ++ni) {
                bf16x8 bv;
                #pragma unroll
                for (int e = 0; e < 8; ++e)
                    bv[e] = (short)vbuf[(ks * 32 + lhi * 8 + e) * 64 + ni * 16 + llo];
                o[ni] = __builtin_amdgcn_mfma_f32_16x16x32_bf16(pa[ks], bv, o[ni], 0, 0, 0);
            }
        }
        __syncthreads();
    }

    // epilogue: ctx[b, s, h*hd] bf16
    const int b = bh >> 4, h = bh & 15;
    float rinv[4];
    #pragma unroll
    for (int j = 0; j < 4; ++j) rinv[j] = 1.0f / l_run[j];
    #pragma unroll
    for (int ni = 0; ni < 4; ++ni) {
        #pragma unroll
        for (int j = 0; j < 4; ++j) {
            int srow = qrow0 + lhi * 4 + j;
            int hd = ni * 16 + llo;
            ctx[(size_t)(b * SS + srow) * DD + h * HDIM + hd] = f2bf(o[ni][j] * rinv[j]);
        }
    }
}

// ---------------------------------------------------------------------------
// Kernel 3: output projection.  out[m,n] = sum_k ctx[m,k]*Wo[n,k] + bo[n]
// A (ctx bf16) via global_load_lds; B (Wo f32) reg-stage + convert.
// ---------------------------------------------------------------------------
__global__ __launch_bounds__(256) void out_gemm(
    const unsigned short* __restrict__ ctx,
    const float* __restrict__ Wo,
    const float* __restrict__ bo,
    float* __restrict__ out)
{
    const int bn = blockIdx.x, bm = blockIdx.y;
    const int tid = threadIdx.x;
    const int wid = tid >> 6, lane = tid & 63;
    const int wr = wid >> 1, wc = wid & 1;
    const int lhi = lane >> 4, llo = lane & 15;

    __shared__ unsigned short As[2][128 * 32];
    __shared__ unsigned short Bs[2][128 * 32];

    const int m0 = bm * 128, n0 = bn * 128;
    const int brow = tid >> 1, bhalf = tid & 1;

    auto stageA = [&](int buf, int kt) {
        #pragma unroll
        for (int j = 0; j < 2; ++j) {
            int chunk = j * 256 + wid * 64 + lane;
            int row = chunk >> 2, sub = chunk & 3;
            gload16(ctx + (size_t)(m0 + row) * DD + kt * 32 + sub * 8,
                    &As[buf][(j * 256 + wid * 64) * 8]);
        }
    };
    auto loadB = [&](int kt, f32x4v* r) {
        const float* p = Wo + (size_t)(n0 + brow) * DD + kt * 32 + bhalf * 16;
        r[0] = *(const f32x4v*)(p);
        r[1] = *(const f32x4v*)(p + 4);
        r[2] = *(const f32x4v*)(p + 8);
        r[3] = *(const f32x4v*)(p + 12);
    };
    auto writeB = [&](int buf, const f32x4v* r) {
        bf16x8 p0, p1;
        #pragma unroll
        for (int e = 0; e < 4; ++e) {
            p0[e]     = (short)f2bf(r[0][e]);
            p0[e + 4] = (short)f2bf(r[1][e]);
            p1[e]     = (short)f2bf(r[2][e]);
            p1[e + 4] = (short)f2bf(r[3][e]);
        }
        *(bf16x8*)&Bs[buf][brow * 32 + bhalf * 16]     = p0;
        *(bf16x8*)&Bs[buf][brow * 32 + bhalf * 16 + 8] = p1;
    };

    f32x4v acc[4][4] = {};
    f32x4v br[4];

    stageA(0, 0);
    loadB(0, br);
    writeB(0, br);
    __syncthreads();

    for (int kt = 0; kt < 32; ++kt) {
        int cur = kt & 1;
        if (kt < 31) { loadB(kt + 1, br); stageA(cur ^ 1, kt + 1); }

        bf16x8 af[4], bfr[4];
        #pragma unroll
        for (int i = 0; i < 4; ++i)
            af[i] = *(const bf16x8*)&As[cur][(wr * 64 + i * 16 + llo) * 32 + lhi * 8];
        #pragma unroll
        for (int i = 0; i < 4; ++i)
            bfr[i] = *(const bf16x8*)&Bs[cur][(wc * 64 + i * 16 + llo) * 32 + lhi * 8];

        #pragma unroll
        for (int i = 0; i < 4; ++i)
            #pragma unroll
            for (int j = 0; j < 4; ++j)
                acc[i][j] = __builtin_amdgcn_mfma_f32_16x16x32_bf16(af[i], bfr[j], acc[i][j], 0, 0, 0);

        if (kt < 31) writeB(cur ^ 1, br);
        __syncthreads();
    }

    #pragma unroll
    for (int j = 0; j < 4; ++j) {
        int ncol = n0 + wc * 64 + j * 16 + llo;
        float bias = bo[ncol];
        #pragma unroll
        for (int i = 0; i < 4; ++i) {
            #pragma unroll
            for (int r = 0; r < 4; ++r) {
                int mrow = m0 + wr * 64 + i * 16 + lhi * 4 + r;
                out[(size_t)mrow * DD + ncol] = acc[i][j][r] + bias;
            }
        }
    }
}

extern "C" void kernel_launch(void* const* d_in, const int* in_sizes, int n_in,
                              void* d_out, int out_size, void* d_ws, size_t ws_size,
                              hipStream_t stream) {
    const float* x  = (const float*)d_in[0];
    const float* Wq = (const float*)d_in[1];
    const float* Wk = (const float*)d_in[2];
    const float* Wv = (const float*)d_in[3];
    const float* Wo = (const float*)d_in[4];
    const float* bo = (const float*)d_in[5];
    float* out = (float*)d_out;

    // workspace (bf16 ushorts), 32 MB peak (Round-1-proven budget):
    //   xb [0,4M) | q [4M,8M) | k [8M,12M) | v [12M,16M) ; ctx aliases xb
    unsigned short* xb   = (unsigned short*)d_ws;
    unsigned short* q_ws = xb   + (size_t)MM * DD;
    unsigned short* k_ws = q_ws + (size_t)MM * DD;
    unsigned short* v_ws = k_ws + (size_t)MM * DD;
    unsigned short* ctx  = xb;   // xb dead after qkv_gemm

    convert_x<<<4096, 256, 0, stream>>>(x, xb);
    qkv_gemm<<<dim3(8, 32, 3), 256, 0, stream>>>(xb, Wq, Wk, Wv, q_ws, k_ws, v_ws);
    attn_kernel<<<dim3(16, 64), 256, 0, stream>>>(q_ws, k_ws, v_ws, ctx);
    out_gemm<<<dim3(8, 32), 256, 0, stream>>>(ctx, Wo, bo, out);
}

// Round 12
// 202.199 us; speedup vs baseline: 1.2449x; 1.1902x over previous
//
#include <hip/hip_runtime.h>
#include <hip/hip_bf16.h>

// Problem constants
#define BB 4
#define SS 1024
#define DD 1024
#define HH 16
#define HDIM 64
#define MM (BB*SS)   // 4096

typedef __attribute__((ext_vector_type(8))) short  bf16x8;
typedef __attribute__((ext_vector_type(4))) float  f32x4v;
typedef __attribute__((ext_vector_type(4))) unsigned short u16x4;

static __device__ __forceinline__ unsigned short f2bf(float f) {
    union { float f; unsigned u; } v; v.f = f;
    unsigned r = v.u + 0x7fff + ((v.u >> 16) & 1);   // round-to-nearest-even
    return (unsigned short)(r >> 16);
}

// async global->LDS, 16B per lane. LDS dest must be wave-uniform base (HW adds lane*16).
static __device__ __forceinline__ void gload16(const void* g, const void* lds_uniform_base) {
    __builtin_amdgcn_global_load_lds(
        (const __attribute__((address_space(1))) unsigned int*)(uintptr_t)g,
        (__attribute__((address_space(3))) unsigned int*)(uintptr_t)lds_uniform_base,
        16, 0, 0);
}

// ---------------------------------------------------------------------------
// Kernel 0a: f32 -> bf16 conversion of x (8 MB out).  4096 blocks x 256.
// ---------------------------------------------------------------------------
__global__ __launch_bounds__(256) void convert_x(
    const float* __restrict__ x, unsigned short* __restrict__ xb)
{
    size_t i = ((size_t)blockIdx.x * 256 + threadIdx.x) * 4;
    f32x4v v = *(const f32x4v*)(x + i);
    u16x4 o;
    o[0] = f2bf(v[0]); o[1] = f2bf(v[1]); o[2] = f2bf(v[2]); o[3] = f2bf(v[3]);
    *(u16x4*)(xb + i) = o;
}

// ---------------------------------------------------------------------------
// Kernel 0b: f32 -> bf16 conversion of the 4 weight matrices. grid (1024, 4).
// ---------------------------------------------------------------------------
__global__ __launch_bounds__(256) void convert_w(
    const float* __restrict__ Wq, const float* __restrict__ Wk,
    const float* __restrict__ Wv, const float* __restrict__ Wo,
    unsigned short* __restrict__ wqb, unsigned short* __restrict__ wkb,
    unsigned short* __restrict__ wvb, unsigned short* __restrict__ wob)
{
    const int seg = blockIdx.y;
    const float* src = (seg == 0) ? Wq : (seg == 1) ? Wk : (seg == 2) ? Wv : Wo;
    unsigned short* dst = (seg == 0) ? wqb : (seg == 1) ? wkb : (seg == 2) ? wvb : wob;
    size_t i = ((size_t)blockIdx.x * 256 + threadIdx.x) * 4;
    f32x4v v = *(const f32x4v*)(src + i);
    u16x4 o;
    o[0] = f2bf(v[0]); o[1] = f2bf(v[1]); o[2] = f2bf(v[2]); o[3] = f2bf(v[3]);
    *(u16x4*)(dst + i) = o;
}

// ---------------------------------------------------------------------------
// Shared epilogue: write Q/K to [b,h,s,hd] (Q scaled 1/8); V transposed to
// [b,h,hd,s] with 8 B vector writes.
// ---------------------------------------------------------------------------
static __device__ __forceinline__ void qkv_epilogue(
    int bz, int m0, int n0, int wr, int wc, int lhi, int llo,
    const f32x4v acc[4][4], unsigned short* outp)
{
    if (bz == 2) {
        #pragma unroll
        for (int i = 0; i < 4; ++i) {
            #pragma unroll
            for (int j = 0; j < 4; ++j) {
                int mb = m0 + wr * 64 + i * 16 + lhi * 4;   // 4 consecutive s
                int ncol = n0 + wc * 64 + j * 16 + llo;
                u16x4 o4;
                #pragma unroll
                for (int r = 0; r < 4; ++r) o4[r] = f2bf(acc[i][j][r]);
                size_t idx = ((size_t)((mb >> 10) * HH + (ncol >> 6)) * HDIM + (ncol & 63)) * SS + (mb & 1023);
                *(u16x4*)(outp + idx) = o4;
            }
        }
    } else {
        const float sc = (bz == 0) ? 0.125f : 1.0f;
        #pragma unroll
        for (int i = 0; i < 4; ++i) {
            #pragma unroll
            for (int j = 0; j < 4; ++j) {
                #pragma unroll
                for (int r = 0; r < 4; ++r) {
                    int mrow = m0 + wr * 64 + i * 16 + lhi * 4 + r;
                    int ncol = n0 + wc * 64 + j * 16 + llo;
                    size_t idx = ((size_t)((mrow >> 10) * HH + (ncol >> 6)) * SS + (mrow & 1023)) * HDIM + (ncol & 63);
                    outp[idx] = f2bf(acc[i][j][r] * sc);
                }
            }
        }
    }
}

// ---------------------------------------------------------------------------
// Kernel 1a: QKV projection, preconverted weights (both sides global_load_lds)
// ---------------------------------------------------------------------------
__global__ __launch_bounds__(256) void qkv_gemm_pc(
    const unsigned short* __restrict__ xb,
    const unsigned short* __restrict__ wqb, const unsigned short* __restrict__ wkb,
    const unsigned short* __restrict__ wvb,
    unsigned short* __restrict__ q_ws, unsigned short* __restrict__ k_ws,
    unsigned short* __restrict__ v_ws)
{
    const int bn = blockIdx.x, bm = blockIdx.y, bz = blockIdx.z;
    const unsigned short* W = (bz == 0) ? wqb : (bz == 1) ? wkb : wvb;
    unsigned short* outp = (bz == 0) ? q_ws : (bz == 1) ? k_ws : v_ws;

    const int tid = threadIdx.x;
    const int wid = tid >> 6, lane = tid & 63;
    const int wr = wid >> 1, wc = wid & 1;
    const int lhi = lane >> 4, llo = lane & 15;

    __shared__ unsigned short As[2][128 * 32];
    __shared__ unsigned short Bs[2][128 * 32];

    const int m0 = bm * 128, n0 = bn * 128;

    auto stage = [&](int buf, int kt) {
        #pragma unroll
        for (int j = 0; j < 2; ++j) {
            int chunk = j * 256 + wid * 64 + lane;
            int row = chunk >> 2, sub = chunk & 3;
            gload16(xb + (size_t)(m0 + row) * DD + kt * 32 + sub * 8,
                    &As[buf][(j * 256 + wid * 64) * 8]);
            gload16(W + (size_t)(n0 + row) * DD + kt * 32 + sub * 8,
                    &Bs[buf][(j * 256 + wid * 64) * 8]);
        }
    };

    f32x4v acc[4][4] = {};
    stage(0, 0);
    __syncthreads();

    for (int kt = 0; kt < 32; ++kt) {
        int cur = kt & 1;
        if (kt < 31) stage(cur ^ 1, kt + 1);

        bf16x8 af[4], bfr[4];
        #pragma unroll
        for (int i = 0; i < 4; ++i)
            af[i] = *(const bf16x8*)&As[cur][(wr * 64 + i * 16 + llo) * 32 + lhi * 8];
        #pragma unroll
        for (int i = 0; i < 4; ++i)
            bfr[i] = *(const bf16x8*)&Bs[cur][(wc * 64 + i * 16 + llo) * 32 + lhi * 8];

        #pragma unroll
        for (int i = 0; i < 4; ++i)
            #pragma unroll
            for (int j = 0; j < 4; ++j)
                acc[i][j] = __builtin_amdgcn_mfma_f32_16x16x32_bf16(af[i], bfr[j], acc[i][j], 0, 0, 0);
        __syncthreads();
    }

    qkv_epilogue(bz, m0, n0, wr, wc, lhi, llo, acc, outp);
}

// ---------------------------------------------------------------------------
// Kernel 1b: QKV projection, reg-staged f32 weights (fallback, proven)
// ---------------------------------------------------------------------------
__global__ __launch_bounds__(256) void qkv_gemm_rs(
    const unsigned short* __restrict__ xb,
    const float* __restrict__ Wq, const float* __restrict__ Wk,
    const float* __restrict__ Wv,
    unsigned short* __restrict__ q_ws, unsigned short* __restrict__ k_ws,
    unsigned short* __restrict__ v_ws)
{
    const int bn = blockIdx.x, bm = blockIdx.y, bz = blockIdx.z;
    const float* W = (bz == 0) ? Wq : (bz == 1) ? Wk : Wv;
    unsigned short* outp = (bz == 0) ? q_ws : (bz == 1) ? k_ws : v_ws;

    const int tid = threadIdx.x;
    const int wid = tid >> 6, lane = tid & 63;
    const int wr = wid >> 1, wc = wid & 1;
    const int lhi = lane >> 4, llo = lane & 15;

    __shared__ unsigned short As[2][128 * 32];
    __shared__ unsigned short Bs[2][128 * 32];

    const int m0 = bm * 128, n0 = bn * 128;
    const int brow = tid >> 1, bhalf = tid & 1;

    auto stageA = [&](int buf, int kt) {
        #pragma unroll
        for (int j = 0; j < 2; ++j) {
            int chunk = j * 256 + wid * 64 + lane;
            int row = chunk >> 2, sub = chunk & 3;
            gload16(xb + (size_t)(m0 + row) * DD + kt * 32 + sub * 8,
                    &As[buf][(j * 256 + wid * 64) * 8]);
        }
    };
    auto loadB = [&](int kt, f32x4v* r) {
        const float* p = W + (size_t)(n0 + brow) * DD + kt * 32 + bhalf * 16;
        r[0] = *(const f32x4v*)(p);
        r[1] = *(const f32x4v*)(p + 4);
        r[2] = *(const f32x4v*)(p + 8);
        r[3] = *(const f32x4v*)(p + 12);
    };
    auto writeB = [&](int buf, const f32x4v* r) {
        bf16x8 p0, p1;
        #pragma unroll
        for (int e = 0; e < 4; ++e) {
            p0[e]     = (short)f2bf(r[0][e]);
            p0[e + 4] = (short)f2bf(r[1][e]);
            p1[e]     = (short)f2bf(r[2][e]);
            p1[e + 4] = (short)f2bf(r[3][e]);
        }
        *(bf16x8*)&Bs[buf][brow * 32 + bhalf * 16]     = p0;
        *(bf16x8*)&Bs[buf][brow * 32 + bhalf * 16 + 8] = p1;
    };

    f32x4v acc[4][4] = {};
    f32x4v br[4];

    stageA(0, 0);
    loadB(0, br);
    writeB(0, br);
    __syncthreads();

    for (int kt = 0; kt < 32; ++kt) {
        int cur = kt & 1;
        if (kt < 31) { loadB(kt + 1, br); stageA(cur ^ 1, kt + 1); }

        bf16x8 af[4], bfr[4];
        #pragma unroll
        for (int i = 0; i < 4; ++i)
            af[i] = *(const bf16x8*)&As[cur][(wr * 64 + i * 16 + llo) * 32 + lhi * 8];
        #pragma unroll
        for (int i = 0; i < 4; ++i)
            bfr[i] = *(const bf16x8*)&Bs[cur][(wc * 64 + i * 16 + llo) * 32 + lhi * 8];

        #pragma unroll
        for (int i = 0; i < 4; ++i)
            #pragma unroll
            for (int j = 0; j < 4; ++j)
                acc[i][j] = __builtin_amdgcn_mfma_f32_16x16x32_bf16(af[i], bfr[j], acc[i][j], 0, 0, 0);

        if (kt < 31) writeB(cur ^ 1, br);
        __syncthreads();
    }

    qkv_epilogue(bz, m0, n0, wr, wc, lhi, llo, acc, outp);
}

// ---------------------------------------------------------------------------
// Kernel 2: flash attention.  QBLK=64 (16 rows/wave), KVBLK=64, dbuf staging.
// K (rows) and V^T (rows) both staged via gload16 with rule-21 XOR-swizzled
// global source; both consumed via swizzled ds_read_b128.
// ---------------------------------------------------------------------------
__global__ __launch_bounds__(256) void attn_kernel(
    const unsigned short* __restrict__ q_ws,
    const unsigned short* __restrict__ k_ws,
    const unsigned short* __restrict__ vt_ws,   // V^T: [b,h,hd,s]
    unsigned short* __restrict__ ctx)
{
    const int qt = blockIdx.x;   // 0..15
    const int bh = blockIdx.y;   // 0..63
    const int tid = threadIdx.x, wid = tid >> 6, lane = tid & 63;
    const int lhi = lane >> 4, llo = lane & 15;

    __shared__ unsigned short Ks[2][64 * 64];   // swizzled rows of K
    __shared__ unsigned short Vs[2][64 * 64];   // swizzled rows of V^T
    __shared__ unsigned short Ps[4][16 * 72];   // per-wave P tile

    const size_t basekv = (size_t)bh * SS * HDIM;   // same for K and V^T
    const int qrow0 = qt * 64 + wid * 16;

    // Q fragments in registers (already pre-scaled by 1/8 in qkv epilogue)
    bf16x8 aq[2];
    #pragma unroll
    for (int ks = 0; ks < 2; ++ks)
        aq[ks] = *(const bf16x8*)(q_ws + basekv + (size_t)(qrow0 + llo) * HDIM + ks * 32 + lhi * 8);

    auto stage = [&](int buf, int kvt) {
        #pragma unroll
        for (int j = 0; j < 2; ++j) {
            int chunk = j * 256 + wid * 64 + lane;
            int row = chunk >> 3, sub = chunk & 7;
            int ssub = (sub ^ (row & 7)) * 8;
            // K rows: [kv row][hd], inverse-swizzled source
            gload16(k_ws + basekv + (size_t)(kvt * 64 + row) * HDIM + ssub,
                    &Ks[buf][(j * 256 + wid * 64) * 8]);
            // V^T rows: [hd row][s], inverse-swizzled source
            gload16(vt_ws + basekv + (size_t)row * SS + kvt * 64 + ssub,
                    &Vs[buf][(j * 256 + wid * 64) * 8]);
        }
    };

    f32x4v o[4] = {};
    float m_run[4], l_run[4];
    #pragma unroll
    for (int j = 0; j < 4; ++j) { m_run[j] = -1e30f; l_run[j] = 0.f; }

    stage(0, 0);
    __syncthreads();

    for (int kvt = 0; kvt < 16; ++kvt) {
        const int cur = kvt & 1;
        if (kvt < 15) stage(cur ^ 1, kvt + 1);

        // ---- S = Q K^T (swizzled read of K) ----
        const char* kbuf = (const char*)&Ks[cur][0];
        f32x4v s[4] = {};
        #pragma unroll
        for (int ni = 0; ni < 4; ++ni) {
            int row = ni * 16 + llo;
            #pragma unroll
            for (int ks = 0; ks < 2; ++ks) {
                int colb = (ks * 64 + lhi * 16) ^ ((llo & 7) << 4);
                bf16x8 bk = *(const bf16x8*)(kbuf + row * 128 + colb);
                s[ni] = __builtin_amdgcn_mfma_f32_16x16x32_bf16(aq[ks], bk, s[ni], 0, 0, 0);
            }
        }

        // ---- online softmax (rows j per lane, cols across 16-lane groups x 4 blocks) ----
        #pragma unroll
        for (int j = 0; j < 4; ++j) {
            float tmax = fmaxf(fmaxf(s[0][j], s[1][j]), fmaxf(s[2][j], s[3][j]));
            #pragma unroll
            for (int off = 1; off < 16; off <<= 1)
                tmax = fmaxf(tmax, __shfl_xor(tmax, off, 64));
            float mn = fmaxf(m_run[j], tmax);
            float alpha = __expf(m_run[j] - mn);
            float rs = 0.f;
            #pragma unroll
            for (int ni = 0; ni < 4; ++ni) {
                float p = __expf(s[ni][j] - mn);
                s[ni][j] = p;
                rs += p;
            }
            #pragma unroll
            for (int off = 1; off < 16; off <<= 1)
                rs += __shfl_xor(rs, off, 64);
            l_run[j] = l_run[j] * alpha + rs;
            m_run[j] = mn;
            #pragma unroll
            for (int ni = 0; ni < 4; ++ni) o[ni][j] *= alpha;
        }

        // ---- P -> per-wave LDS, read back as A-fragments ----
        unsigned short* pw = Ps[wid];
        #pragma unroll
        for (int ni = 0; ni < 4; ++ni)
            #pragma unroll
            for (int j = 0; j < 4; ++j)
                pw[(lhi * 4 + j) * 72 + ni * 16 + llo] = f2bf(s[ni][j]);

        asm volatile("s_waitcnt lgkmcnt(0)" ::: "memory");
        __builtin_amdgcn_sched_barrier(0);

        bf16x8 pa[2];
        #pragma unroll
        for (int ks = 0; ks < 2; ++ks)
            pa[ks] = *(const bf16x8*)(pw + llo * 72 + ks * 32 + lhi * 8);

        // ---- O += P V (swizzled b128 reads of V^T rows) ----
        const char* vbuf = (const char*)&Vs[cur][0];
        #pragma unroll
        for (int ks = 0; ks < 2; ++ks) {
            #pragma unroll
            for (int ni = 0; ni < 4; ++ni) {
                int colb = (ks * 64 + lhi * 16) ^ ((llo & 7) << 4);
                bf16x8 bv = *(const bf16x8*)(vbuf + (ni * 16 + llo) * 128 + colb);
                o[ni] = __builtin_amdgcn_mfma_f32_16x16x32_bf16(pa[ks], bv, o[ni], 0, 0, 0);
            }
        }
        __syncthreads();
    }

    // epilogue: ctx[b, s, h*hd] bf16
    const int b = bh >> 4, h = bh & 15;
    float rinv[4];
    #pragma unroll
    for (int j = 0; j < 4; ++j) rinv[j] = 1.0f / l_run[j];
    #pragma unroll
    for (int ni = 0; ni < 4; ++ni) {
        #pragma unroll
        for (int j = 0; j < 4; ++j) {
            int srow = qrow0 + lhi * 4 + j;
            int hd = ni * 16 + llo;
            ctx[(size_t)(b * SS + srow) * DD + h * HDIM + hd] = f2bf(o[ni][j] * rinv[j]);
        }
    }
}

// ---------------------------------------------------------------------------
// Kernel 3a: output projection, preconverted Wo (both sides global_load_lds)
// ---------------------------------------------------------------------------
__global__ __launch_bounds__(256) void out_gemm_pc(
    const unsigned short* __restrict__ ctx,
    const unsigned short* __restrict__ wob,
    const float* __restrict__ bo,
    float* __restrict__ out)
{
    const int bn = blockIdx.x, bm = blockIdx.y;
    const int tid = threadIdx.x;
    const int wid = tid >> 6, lane = tid & 63;
    const int wr = wid >> 1, wc = wid & 1;
    const int lhi = lane >> 4, llo = lane & 15;

    __shared__ unsigned short As[2][128 * 32];
    __shared__ unsigned short Bs[2][128 * 32];

    const int m0 = bm * 128, n0 = bn * 128;

    auto stage = [&](int buf, int kt) {
        #pragma unroll
        for (int j = 0; j < 2; ++j) {
            int chunk = j * 256 + wid * 64 + lane;
            int row = chunk >> 2, sub = chunk & 3;
            gload16(ctx + (size_t)(m0 + row) * DD + kt * 32 + sub * 8,
                    &As[buf][(j * 256 + wid * 64) * 8]);
            gload16(wob + (size_t)(n0 + row) * DD + kt * 32 + sub * 8,
                    &Bs[buf][(j * 256 + wid * 64) * 8]);
        }
    };

    f32x4v acc[4][4] = {};
    stage(0, 0);
    __syncthreads();

    for (int kt = 0; kt < 32; ++kt) {
        int cur = kt & 1;
        if (kt < 31) stage(cur ^ 1, kt + 1);

        bf16x8 af[4], bfr[4];
        #pragma unroll
        for (int i = 0; i < 4; ++i)
            af[i] = *(const bf16x8*)&As[cur][(wr * 64 + i * 16 + llo) * 32 + lhi * 8];
        #pragma unroll
        for (int i = 0; i < 4; ++i)
            bfr[i] = *(const bf16x8*)&Bs[cur][(wc * 64 + i * 16 + llo) * 32 + lhi * 8];

        #pragma unroll
        for (int i = 0; i < 4; ++i)
            #pragma unroll
            for (int j = 0; j < 4; ++j)
                acc[i][j] = __builtin_amdgcn_mfma_f32_16x16x32_bf16(af[i], bfr[j], acc[i][j], 0, 0, 0);
        __syncthreads();
    }

    #pragma unroll
    for (int j = 0; j < 4; ++j) {
        int ncol = n0 + wc * 64 + j * 16 + llo;
        float bias = bo[ncol];
        #pragma unroll
        for (int i = 0; i < 4; ++i) {
            #pragma unroll
            for (int r = 0; r < 4; ++r) {
                int mrow = m0 + wr * 64 + i * 16 + lhi * 4 + r;
                out[(size_t)mrow * DD + ncol] = acc[i][j][r] + bias;
            }
        }
    }
}

// ---------------------------------------------------------------------------
// Kernel 3b: output projection, reg-staged f32 Wo (fallback, proven)
// ---------------------------------------------------------------------------
__global__ __launch_bounds__(256) void out_gemm_rs(
    const unsigned short* __restrict__ ctx,
    const float* __restrict__ Wo,
    const float* __restrict__ bo,
    float* __restrict__ out)
{
    const int bn = blockIdx.x, bm = blockIdx.y;
    const int tid = threadIdx.x;
    const int wid = tid >> 6, lane = tid & 63;
    const int wr = wid >> 1, wc = wid & 1;
    const int lhi = lane >> 4, llo = lane & 15;

    __shared__ unsigned short As[2][128 * 32];
    __shared__ unsigned short Bs[2][128 * 32];

    const int m0 = bm * 128, n0 = bn * 128;
    const int brow = tid >> 1, bhalf = tid & 1;

    auto stageA = [&](int buf, int kt) {
        #pragma unroll
        for (int j = 0; j < 2; ++j) {
            int chunk = j * 256 + wid * 64 + lane;
            int row = chunk >> 2, sub = chunk & 3;
            gload16(ctx + (size_t)(m0 + row) * DD + kt * 32 + sub * 8,
                    &As[buf][(j * 256 + wid * 64) * 8]);
        }
    };
    auto loadB = [&](int kt, f32x4v* r) {
        const float* p = Wo + (size_t)(n0 + brow) * DD + kt * 32 + bhalf * 16;
        r[0] = *(const f32x4v*)(p);
        r[1] = *(const f32x4v*)(p + 4);
        r[2] = *(const f32x4v*)(p + 8);
        r[3] = *(const f32x4v*)(p + 12);
    };
    auto writeB = [&](int buf, const f32x4v* r) {
        bf16x8 p0, p1;
        #pragma unroll
        for (int e = 0; e < 4; ++e) {
            p0[e]     = (short)f2bf(r[0][e]);
            p0[e + 4] = (short)f2bf(r[1][e]);
            p1[e]     = (short)f2bf(r[2][e]);
            p1[e + 4] = (short)f2bf(r[3][e]);
        }
        *(bf16x8*)&Bs[buf][brow * 32 + bhalf * 16]     = p0;
        *(bf16x8*)&Bs[buf][brow * 32 + bhalf * 16 + 8] = p1;
    };

    f32x4v acc[4][4] = {};
    f32x4v br[4];

    stageA(0, 0);
    loadB(0, br);
    writeB(0, br);
    __syncthreads();

    for (int kt = 0; kt < 32; ++kt) {
        int cur = kt & 1;
        if (kt < 31) { loadB(kt + 1, br); stageA(cur ^ 1, kt + 1); }

        bf16x8 af[4], bfr[4];
        #pragma unroll
        for (int i = 0; i < 4; ++i)
            af[i] = *(const bf16x8*)&As[cur][(wr * 64 + i * 16 + llo) * 32 + lhi * 8];
        #pragma unroll
        for (int i = 0; i < 4; ++i)
            bfr[i] = *(const bf16x8*)&Bs[cur][(wc * 64 + i * 16 + llo) * 32 + lhi * 8];

        #pragma unroll
        for (int i = 0; i < 4; ++i)
            #pragma unroll
            for (int j = 0; j < 4; ++j)
                acc[i][j] = __builtin_amdgcn_mfma_f32_16x16x32_bf16(af[i], bfr[j], acc[i][j], 0, 0, 0);

        if (kt < 31) writeB(cur ^ 1, br);
        __syncthreads();
    }

    #pragma unroll
    for (int j = 0; j < 4; ++j) {
        int ncol = n0 + wc * 64 + j * 16 + llo;
        float bias = bo[ncol];
        #pragma unroll
        for (int i = 0; i < 4; ++i) {
            #pragma unroll
            for (int r = 0; r < 4; ++r) {
                int mrow = m0 + wr * 64 + i * 16 + lhi * 4 + r;
                out[(size_t)mrow * DD + ncol] = acc[i][j][r] + bias;
            }
        }
    }
}

extern "C" void kernel_launch(void* const* d_in, const int* in_sizes, int n_in,
                              void* d_out, int out_size, void* d_ws, size_t ws_size,
                              hipStream_t stream) {
    const float* x  = (const float*)d_in[0];
    const float* Wq = (const float*)d_in[1];
    const float* Wk = (const float*)d_in[2];
    const float* Wv = (const float*)d_in[3];
    const float* Wo = (const float*)d_in[4];
    const float* bo = (const float*)d_in[5];
    float* out = (float*)d_out;

    const bool preconv = ws_size >= (size_t)40 * 1024 * 1024;

    if (preconv) {
        // 40 MB layout (shorts): xb[0,4M) wq[4M,5M) wk[5M,6M) wv[6M,7M)
        //                        wo[7M,8M) q[8M,12M) k[12M,16M) v[16M,20M)
        unsigned short* xb   = (unsigned short*)d_ws;
        unsigned short* wqb  = xb   + (size_t)MM * DD;
        unsigned short* wkb  = wqb  + (size_t)DD * DD;
        unsigned short* wvb  = wkb  + (size_t)DD * DD;
        unsigned short* wob  = wvb  + (size_t)DD * DD;
        unsigned short* q_ws = wob  + (size_t)DD * DD;
        unsigned short* k_ws = q_ws + (size_t)MM * DD;
        unsigned short* v_ws = k_ws + (size_t)MM * DD;
        unsigned short* ctx  = xb;   // xb dead after qkv_gemm

        convert_x<<<4096, 256, 0, stream>>>(x, xb);
        convert_w<<<dim3(1024, 4), 256, 0, stream>>>(Wq, Wk, Wv, Wo, wqb, wkb, wvb, wob);
        qkv_gemm_pc<<<dim3(8, 32, 3), 256, 0, stream>>>(xb, wqb, wkb, wvb, q_ws, k_ws, v_ws);
        attn_kernel<<<dim3(16, 64), 256, 0, stream>>>(q_ws, k_ws, v_ws, ctx);
        out_gemm_pc<<<dim3(8, 32), 256, 0, stream>>>(ctx, wob, bo, out);
    } else {
        // 32 MB layout (shorts): xb[0,4M) q[4M,8M) k[8M,12M) v[12M,16M)
        unsigned short* xb   = (unsigned short*)d_ws;
        unsigned short* q_ws = xb   + (size_t)MM * DD;
        unsigned short* k_ws = q_ws + (size_t)MM * DD;
        unsigned short* v_ws = k_ws + (size_t)MM * DD;
        unsigned short* ctx  = xb;

        convert_x<<<4096, 256, 0, stream>>>(x, xb);
        qkv_gemm_rs<<<dim3(8, 32, 3), 256, 0, stream>>>(xb, Wq, Wk, Wv, q_ws, k_ws, v_ws);
        attn_kernel<<<dim3(16, 64), 256, 0, stream>>>(q_ws, k_ws, v_ws, ctx);
        out_gemm_rs<<<dim3(8, 32), 256, 0, stream>>>(ctx, Wo, bo, out);
    }
}